// Round 1
// baseline (1062.253 us; speedup 1.0000x reference)
//
#include <hip/hip_runtime.h>

typedef unsigned short u16;
typedef unsigned int   u32;
typedef float  f32x4  __attribute__((ext_vector_type(4)));
typedef short  bf16x8 __attribute__((ext_vector_type(8)));
typedef u16    u16x4  __attribute__((ext_vector_type(4)));

#define BQ 8
#define SQ 4096
#define DQ 1024
#define NQ 2048      // 2*D
#define MQ 32768     // B*S
#define KQ 1024
#define CCH 64       // chunks per sequence
#define TCH 64       // timesteps per chunk (CCH*TCH == SQ)

__device__ __forceinline__ float bf2f(u16 u){
  union { u32 i; float f; } v; v.i = ((u32)u) << 16; return v.f;
}
__device__ __forceinline__ u16 f2bf(float f){
  union { float f; u32 i; } v; v.f = f;
  u32 r = v.i + 0x7fffu + ((v.i >> 16) & 1u);   // round-to-nearest-even
  return (u16)(r >> 16);
}

// a = 1 - sigmoid(gate) = sigmoid(-gate);  bv = sigmoid(gate) * g(hidden)
// g(x) = x + 0.5 (x>=0) else sigmoid(x)
__device__ __forceinline__ void sig_ab(float gate, float hid, float& a, float& bv){
  float eg = __expf(gate);
  float a_ = __builtin_amdgcn_rcpf(1.f + eg);   // eg=inf -> a_=0 (ok)
  float z  = 1.f - a_;
  float eh = __expf(hid);
  float sg = eh * __builtin_amdgcn_rcpf(1.f + eh); // stable for hid<0
  float gval = (hid >= 0.f) ? (hid + 0.5f) : sg;
  a = a_; bv = z * gval;
}

__device__ __forceinline__ void gload_lds16(const u16* g, u16* l){
  __builtin_amdgcn_global_load_lds(
      (const __attribute__((address_space(1))) u32*)g,
      (__attribute__((address_space(3)))       u32*)l,
      16, 0, 0);
}

// ---------------- W transpose + bf16 cast: [L][K][N] f32 -> [L][N][K] bf16 ----
__global__ __launch_bounds__(256) void wt_cast(const float* __restrict__ W,
                                               u16* __restrict__ WT){
  __shared__ float t[64][65];
  const int l  = blockIdx.z;
  const int k0 = blockIdx.x << 6, n0 = blockIdx.y << 6;
  const float* Wl = W  + (size_t)l * KQ * NQ;
  u16*         Tl = WT + (size_t)l * NQ * KQ;
  const int c = threadIdx.x & 63, r4 = threadIdx.x >> 6;
  #pragma unroll
  for (int i = 0; i < 16; ++i){
    int r = i * 4 + r4;
    t[r][c] = Wl[(size_t)(k0 + r) * NQ + n0 + c];
  }
  __syncthreads();
  #pragma unroll
  for (int i = 0; i < 16; ++i){
    int r = i * 4 + r4;
    Tl[(size_t)(n0 + r) * KQ + k0 + c] = f2bf(t[c][r]);
  }
}

// ---------------- LayerNorm (fp32 in) + bf16 cast -----------------------------
__global__ __launch_bounds__(256) void ln_cast(const float* __restrict__ x,
                                               const float* __restrict__ gamma,
                                               const float* __restrict__ beta,
                                               u16* __restrict__ xn){
  const size_t row = blockIdx.x;
  const int tid = threadIdx.x;
  f32x4 xv = *(const f32x4*)(x + row * DQ + tid * 4);
  float s  = xv[0] + xv[1] + xv[2] + xv[3];
  float s2 = xv[0]*xv[0] + xv[1]*xv[1] + xv[2]*xv[2] + xv[3]*xv[3];
  #pragma unroll
  for (int off = 32; off > 0; off >>= 1){
    s  += __shfl_down(s,  off);
    s2 += __shfl_down(s2, off);
  }
  __shared__ float red[8];
  const int wave = tid >> 6, lane = tid & 63;
  if (lane == 0){ red[wave] = s; red[4 + wave] = s2; }
  __syncthreads();
  s  = red[0] + red[1] + red[2] + red[3];
  s2 = red[4] + red[5] + red[6] + red[7];
  const float mean = s * (1.f / DQ);
  float var = fmaxf(s2 * (1.f / DQ) - mean * mean, 0.f);
  const float rstd = rsqrtf(var + 1e-5f);
  f32x4 gv = *(const f32x4*)(gamma + tid * 4);
  f32x4 bv = *(const f32x4*)(beta  + tid * 4);
  u16x4 o;
  #pragma unroll
  for (int e = 0; e < 4; ++e) o[e] = f2bf((xv[e] - mean) * rstd * gv[e] + bv[e]);
  *(u16x4*)(xn + row * DQ + tid * 4) = o;
}

// ---------------- GEMM: gh = xn(bf16) @ W_T^T + b, stored bf16 ---------------
// A: [M][K] bf16 row-major, Bt: [N][K] bf16 row-major (= W transposed)
// 128x128 tile, BK=64, 4 waves (2x2), 16x16x32 MFMA, m97-style structure.
__global__ __launch_bounds__(256) void gemm_k(const u16* __restrict__ A,
                                              const u16* __restrict__ Bt,
                                              const float* __restrict__ bias,
                                              u16* __restrict__ Cg){
  __shared__ u16 As[128 * 64];
  __shared__ u16 Bs[128 * 64];
  const int n0 = blockIdx.x << 7;
  const int m0 = blockIdx.y << 7;
  const int tid  = threadIdx.x;
  const int wave = tid >> 6, lane = tid & 63;
  const int wr = wave >> 1, wc = wave & 1;       // 2x2 waves, 64x64 each
  const int lr = lane & 15;                      // row/col within fragment
  const int lk = (lane >> 4) << 3;               // k-offset: 0,8,16,24
  const int srow = lane >> 3;                    // staging: row within 8-row group
  const int skc  = (lane & 7) << 3;              // staging: k element offset

  f32x4 acc[4][4] = {};

  const u16* Ap = A  + (size_t)(m0 + wave * 8 + srow) * KQ + skc;
  const u16* Bp = Bt + (size_t)(n0 + wave * 8 + srow) * KQ + skc;

  for (int k0 = 0; k0 < KQ; k0 += 64){
    #pragma unroll
    for (int p = 0; p < 4; ++p){
      gload_lds16(Ap + (size_t)(p * 32) * KQ + k0, &As[(p * 32 + wave * 8) * 64]);
      gload_lds16(Bp + (size_t)(p * 32) * KQ + k0, &Bs[(p * 32 + wave * 8) * 64]);
    }
    __syncthreads();
    #pragma unroll
    for (int kk = 0; kk < 64; kk += 32){
      bf16x8 af[4], bfr[4];
      #pragma unroll
      for (int i = 0; i < 4; ++i){
        af[i]  = *(const bf16x8*)&As[(wr * 64 + i * 16 + lr) * 64 + kk + lk];
        bfr[i] = *(const bf16x8*)&Bs[(wc * 64 + i * 16 + lr) * 64 + kk + lk];
      }
      #pragma unroll
      for (int i = 0; i < 4; ++i)
        #pragma unroll
        for (int j = 0; j < 4; ++j)
          acc[i][j] = __builtin_amdgcn_mfma_f32_16x16x32_bf16(af[i], bfr[j], acc[i][j], 0, 0, 0);
    }
    __syncthreads();
  }
  // epilogue: +bias, cast bf16, store. C/D layout: col=lane&15, row=4*(lane>>4)+r
  #pragma unroll
  for (int j = 0; j < 4; ++j){
    const int col = n0 + wc * 64 + j * 16 + lr;
    const float bj = bias[col];
    #pragma unroll
    for (int i = 0; i < 4; ++i){
      const int row0 = m0 + wr * 64 + i * 16 + ((lane >> 4) << 2);
      #pragma unroll
      for (int r = 0; r < 4; ++r)
        Cg[(size_t)(row0 + r) * NQ + col] = f2bf(acc[i][j][r] + bj);
    }
  }
}

// ---------------- scan phase 1: per-chunk aggregates (P = prod a, Q) ---------
__global__ __launch_bounds__(256) void scan1(const u16* __restrict__ gh,
                                             float* __restrict__ P,
                                             float* __restrict__ Q){
  const int b = blockIdx.x >> 6;     // CCH=64
  const int c = blockIdx.x & 63;
  const int d4 = threadIdx.x << 2;
  const u16* base = gh + ((size_t)(b * SQ + c * TCH) * NQ) + d4;
  float p[4] = {1.f,1.f,1.f,1.f}, q[4] = {0.f,0.f,0.f,0.f};
  for (int t = 0; t < TCH; ++t){
    u16x4 gv = *(const u16x4*)(base + (size_t)t * NQ);
    u16x4 hv = *(const u16x4*)(base + (size_t)t * NQ + DQ);
    #pragma unroll
    for (int e = 0; e < 4; ++e){
      float a, bv; sig_ab(bf2f(gv[e]), bf2f(hv[e]), a, bv);
      p[e] *= a; q[e] = a * q[e] + bv;
    }
  }
  const size_t o = ((size_t)blockIdx.x << 10) + d4;
  *(f32x4*)(P + o) = f32x4{p[0], p[1], p[2], p[3]};
  *(f32x4*)(Q + o) = f32x4{q[0], q[1], q[2], q[3]};
}

// ---------------- scan phase 2: scan across chunks; also emits h_last --------
__global__ __launch_bounds__(256) void scan2(const float* __restrict__ P,
                                             const float* __restrict__ Q,
                                             float* __restrict__ hst,
                                             float* __restrict__ hlast){
  const int idx = blockIdx.x * 256 + threadIdx.x;   // 0..B*D-1
  const int b = idx >> 10, d = idx & 1023;
  float h = 0.5f;                                   // h0 = g(0) = 0.5
  for (int c = 0; c < CCH; ++c){
    const size_t o = ((size_t)(b * CCH + c) << 10) + d;
    hst[o] = h;
    h = P[o] * h + Q[o];
  }
  hlast[idx] = h;
}

// ---------------- scan phase 3: replay within chunk, h + residual ------------
__global__ __launch_bounds__(256) void scan3(const u16* __restrict__ gh,
                                             const float* __restrict__ hst,
                                             const float* __restrict__ inp,
                                             float* __restrict__ outp){
  const int b = blockIdx.x >> 6;
  const int c = blockIdx.x & 63;
  const int d4 = threadIdx.x << 2;
  const size_t srow = (size_t)(b * SQ + c * TCH);
  const u16*   base = gh   + srow * NQ + d4;
  const float* ib   = inp  + srow * DQ + d4;
  float*       ob   = outp + srow * DQ + d4;
  const size_t o = ((size_t)blockIdx.x << 10) + d4;
  f32x4 h0 = *(const f32x4*)(hst + o);
  float h[4] = {h0[0], h0[1], h0[2], h0[3]};
  for (int t = 0; t < TCH; ++t){
    u16x4 gv = *(const u16x4*)(base + (size_t)t * NQ);
    u16x4 hh = *(const u16x4*)(base + (size_t)t * NQ + DQ);
    f32x4 iv = *(const f32x4*)(ib + (size_t)t * DQ);
    f32x4 ov;
    #pragma unroll
    for (int e = 0; e < 4; ++e){
      float a, bv; sig_ab(bf2f(gv[e]), bf2f(hh[e]), a, bv);
      h[e] = a * h[e] + bv;
      ov[e] = h[e] + iv[e];
    }
    *(f32x4*)(ob + (size_t)t * DQ) = ov;
  }
}

extern "C" void kernel_launch(void* const* d_in, const int* in_sizes, int n_in,
                              void* d_out, int out_size, void* d_ws, size_t ws_size,
                              hipStream_t stream) {
  const float* x     = (const float*)d_in[0];   // (8,4096,1024)
  const float* gamma = (const float*)d_in[1];   // (3,1024)
  const float* beta  = (const float*)d_in[2];   // (3,1024)
  const float* W     = (const float*)d_in[3];   // (3,1024,2048)
  const float* bias  = (const float*)d_in[4];   // (3,2048)
  float* out = (float*)d_out;                   // 33554432 + 3*8192 floats

  char* ws = (char*)d_ws;
  const size_t ACT = (size_t)MQ * DQ * 4;                 // 128 MiB
  float* bufA = (float*)(ws);
  float* bufB = (float*)(ws + ACT);
  u16*   gh   = (u16*)  (ws + 2 * ACT);                   // MQ*NQ bf16 = 128 MiB
  u16*   xn   = (u16*)  (ws + 3 * ACT);                   // MQ*DQ bf16 = 64 MiB
  u16*   WT   = (u16*)  (ws + 3 * ACT + (size_t)MQ * DQ * 2);
  float* Pa   = (float*)(ws + 3 * ACT + (size_t)MQ * DQ * 2 + (size_t)3 * NQ * KQ * 2);
  float* Qa   = Pa + (size_t)BQ * CCH * DQ;
  float* hst  = Qa + (size_t)BQ * CCH * DQ;

  wt_cast<<<dim3(KQ / 64, NQ / 64, 3), 256, 0, stream>>>(W, WT);

  const float* inp = x;
  for (int l = 0; l < 3; ++l){
    ln_cast<<<MQ, 256, 0, stream>>>(inp, gamma + l * DQ, beta + l * DQ, xn);
    gemm_k<<<dim3(NQ / 128, MQ / 128), 256, 0, stream>>>(
        xn, WT + (size_t)l * NQ * KQ, bias + l * NQ, gh);
    scan1<<<BQ * CCH, 256, 0, stream>>>(gh, Pa, Qa);
    scan2<<<(BQ * DQ) / 256, 256, 0, stream>>>(Pa, Qa, hst, out + (size_t)MQ * DQ + l * BQ * DQ);
    float* o = (l == 2) ? out : (l == 0 ? bufA : bufB);
    scan3<<<BQ * CCH, 256, 0, stream>>>(gh, hst, inp, o);
    inp = o;
  }
}

// Round 3
// 904.908 us; speedup vs baseline: 1.1739x; 1.1739x over previous
//
#include <hip/hip_runtime.h>

typedef unsigned short u16;
typedef unsigned int   u32;
typedef float  f32x4  __attribute__((ext_vector_type(4)));
typedef short  bf16x8 __attribute__((ext_vector_type(8)));
typedef u16    u16x4  __attribute__((ext_vector_type(4)));

#define BQ 8
#define SQ 4096
#define DQ 1024
#define NQ 2048      // 2*D
#define MQ 32768     // B*S
#define KQ 1024
#define CCH 64       // chunks per sequence
#define TCH 64       // timesteps per chunk (CCH*TCH == SQ)
#define NT 16        // K-tiles (KQ/64)

__device__ __forceinline__ float bf2f(u16 u){
  union { u32 i; float f; } v; v.i = ((u32)u) << 16; return v.f;
}
__device__ __forceinline__ u16 f2bf(float f){
  union { float f; u32 i; } v; v.f = f;
  u32 r = v.i + 0x7fffu + ((v.i >> 16) & 1u);   // round-to-nearest-even
  return (u16)(r >> 16);
}

// a = 1 - sigmoid(gate) = sigmoid(-gate);  bv = sigmoid(gate) * g(hidden)
__device__ __forceinline__ void sig_ab(float gate, float hid, float& a, float& bv){
  float eg = __expf(gate);
  float a_ = __builtin_amdgcn_rcpf(1.f + eg);
  float z  = 1.f - a_;
  float eh = __expf(hid);
  float sg = eh * __builtin_amdgcn_rcpf(1.f + eh);
  float gval = (hid >= 0.f) ? (hid + 0.5f) : sg;
  a = a_; bv = z * gval;
}

__device__ __forceinline__ void gload_lds16(const u16* g, u16* l){
  __builtin_amdgcn_global_load_lds(
      (const __attribute__((address_space(1))) u32*)g,
      (__attribute__((address_space(3)))       u32*)l,
      16, 0, 0);
}

// ---------------- W transpose + bf16 cast: [L][K][N] f32 -> [L][N][K] bf16 ----
__global__ __launch_bounds__(256) void wt_cast(const float* __restrict__ W,
                                               u16* __restrict__ WT){
  __shared__ float t[64][65];
  const int l  = blockIdx.z;
  const int k0 = blockIdx.x << 6, n0 = blockIdx.y << 6;
  const float* Wl = W  + (size_t)l * KQ * NQ;
  u16*         Tl = WT + (size_t)l * NQ * KQ;
  const int c = threadIdx.x & 63, r4 = threadIdx.x >> 6;
  #pragma unroll
  for (int i = 0; i < 16; ++i){
    int r = i * 4 + r4;
    t[r][c] = Wl[(size_t)(k0 + r) * NQ + n0 + c];
  }
  __syncthreads();
  #pragma unroll
  for (int i = 0; i < 16; ++i){
    int r = i * 4 + r4;
    Tl[(size_t)(n0 + r) * KQ + k0 + c] = f2bf(t[c][r]);
  }
}

// ---------------- LayerNorm (fp32 in) + bf16 cast -----------------------------
__global__ __launch_bounds__(256) void ln_cast(const float* __restrict__ x,
                                               const float* __restrict__ gamma,
                                               const float* __restrict__ beta,
                                               u16* __restrict__ xn){
  const size_t row = blockIdx.x;
  const int tid = threadIdx.x;
  f32x4 xv = *(const f32x4*)(x + row * DQ + tid * 4);
  float s  = xv[0] + xv[1] + xv[2] + xv[3];
  float s2 = xv[0]*xv[0] + xv[1]*xv[1] + xv[2]*xv[2] + xv[3]*xv[3];
  #pragma unroll
  for (int off = 32; off > 0; off >>= 1){
    s  += __shfl_down(s,  off);
    s2 += __shfl_down(s2, off);
  }
  __shared__ float red[8];
  const int wave = tid >> 6, lane = tid & 63;
  if (lane == 0){ red[wave] = s; red[4 + wave] = s2; }
  __syncthreads();
  s  = red[0] + red[1] + red[2] + red[3];
  s2 = red[4] + red[5] + red[6] + red[7];
  const float mean = s * (1.f / DQ);
  float var = fmaxf(s2 * (1.f / DQ) - mean * mean, 0.f);
  const float rstd = rsqrtf(var + 1e-5f);
  f32x4 gv = *(const f32x4*)(gamma + tid * 4);
  f32x4 bv = *(const f32x4*)(beta  + tid * 4);
  u16x4 o;
  #pragma unroll
  for (int e = 0; e < 4; ++e) o[e] = f2bf((xv[e] - mean) * rstd * gv[e] + bv[e]);
  *(u16x4*)(xn + row * DQ + tid * 4) = o;
}

// ---------------- GEMM: 256x256 tile, BK=64, 8 waves, 8-phase-style schedule --
// A: [M][K] bf16 row-major, Bt: [N][K] bf16 row-major (= W^T).
// LDS: [buf][op A/B][half 128-rows][128][64] bf16, st-swizzled (slot ^= row&7),
// staged via global_load_lds with pre-swizzled global source (rule #21).
// Per K-tile: 4 phases = 4 C-quadrants (qm,qn); each: 12 ds_read_b128 +
// 1 half-tile stage + fenced s_barrier + lgkmcnt(0) + 16 MFMA in setprio(1).
// vmcnt(4) once/tile; vmcnt(0) at t==NT-2 (tail drain — trailing stages are
// skipped there, so vmcnt(4) would no longer cover A1/B1(NT-1); R2 race).
// FENCE around every barrier: s_barrier intrinsic is IntrNoMem — without a
// compiler memory clobber, ds_reads / global_load_lds can be hoisted/sunk
// across phases (WAR race vs async LDS landing; R2 race #2).
__global__ __launch_bounds__(512, 2) void gemm_k8(const u16* __restrict__ A,
                                                  const u16* __restrict__ Bt,
                                                  const float* __restrict__ bias,
                                                  u16* __restrict__ Cg){
  __shared__ u16 lds[2][2][2][8192];   // [buf][op][half][row*64+col] = 128 KiB
  const int bid = blockIdx.x;
  const int swz = ((bid & 7) << 7) | (bid >> 3);   // 1024 wgs, %8==0 -> bijective
  const int bn = swz & 7, bm = swz >> 3;           // XCD owns contiguous bm stripe
  const int n0 = bn << 8, m0 = bm << 8;
  const int tid = threadIdx.x;
  const int w = tid >> 6, lane = tid & 63;
  const int wr = w >> 2, wc = w & 3;               // 2M x 4N wave grid
  const int lr = lane & 15, hi = lane >> 4;
  const int sl8 = lane >> 3;                       // staging row-in-8 (== row&7)
  const int sslot = (lane & 7) ^ sl8;              // pre-swizzled global slot

  f32x4 acc[2][2][4][2] = {};                      // [qm][qn][i][j]

#define FENCE asm volatile("" ::: "memory")
#define BAR do { FENCE; __builtin_amdgcn_s_barrier(); FENCE; } while(0)

#define STAGE(op, hf, kt, pb) do {                                              \
    const u16* gsrc_ = (op) ? Bt : A;                                           \
    const int rb_ = ((op) ? n0 : m0) + ((hf) << 7);                             \
    _Pragma("unroll")                                                           \
    for (int g_ = 0; g_ < 2; ++g_){                                             \
      const int row_ = (w << 4) + (g_ << 3) + sl8;                              \
      gload_lds16(gsrc_ + (size_t)(rb_ + row_) * KQ + ((kt) << 6) + (sslot << 3),\
                  &lds[pb][op][hf][((w << 4) + (g_ << 3)) << 6]);               \
    }                                                                           \
  } while(0)

  // swizzled ds_read: logical (row, 16B-slot) -> byte row*128 + (slot^(row&7))*16
#define LDSRD(dst, base_, row_, slot_) do {                                     \
    const int r_ = (row_);                                                      \
    dst = *(const bf16x8*)((const char*)(base_) +                               \
          ((r_ << 7) + ((((slot_)) ^ (r_ & 7)) << 4)));                         \
  } while(0)

#define PHASE(qm, qn, STG, VMW) do {                                            \
    bf16x8 af_[4][2], bf_[2][2];                                                \
    const u16* Ah_ = &lds[pb][0][qm][0];                                        \
    const u16* Bh_ = &lds[pb][1][qn][0];                                        \
    _Pragma("unroll")                                                           \
    for (int i_ = 0; i_ < 4; ++i_)                                              \
      _Pragma("unroll")                                                         \
      for (int kk_ = 0; kk_ < 2; ++kk_)                                         \
        LDSRD(af_[i_][kk_], Ah_, (wr << 6) + (i_ << 4) + lr, (kk_ << 2) + hi);  \
    _Pragma("unroll")                                                           \
    for (int j_ = 0; j_ < 2; ++j_)                                              \
      _Pragma("unroll")                                                         \
      for (int kk_ = 0; kk_ < 2; ++kk_)                                         \
        LDSRD(bf_[j_][kk_], Bh_, (wc << 5) + (j_ << 4) + lr, (kk_ << 2) + hi);  \
    STG;                                                                        \
    BAR;                                                                        \
    asm volatile("s_waitcnt lgkmcnt(0)" ::: "memory");                          \
    __builtin_amdgcn_s_setprio(1);                                              \
    _Pragma("unroll")                                                           \
    for (int i_ = 0; i_ < 4; ++i_)                                              \
      _Pragma("unroll")                                                         \
      for (int j_ = 0; j_ < 2; ++j_)                                            \
        _Pragma("unroll")                                                       \
        for (int kk_ = 0; kk_ < 2; ++kk_)                                       \
          acc[qm][qn][i_][j_] = __builtin_amdgcn_mfma_f32_16x16x32_bf16(        \
              af_[i_][kk_], bf_[j_][kk_], acc[qm][qn][i_][j_], 0, 0, 0);        \
    __builtin_amdgcn_s_setprio(0);                                              \
    VMW;                                                                        \
    BAR;                                                                        \
  } while(0)

  // prologue: tile0 all 4 halves + tile1 {A0,B0}; vmcnt(4) = tile0 landed
  STAGE(0, 0, 0, 0); STAGE(0, 1, 0, 0); STAGE(1, 0, 0, 0); STAGE(1, 1, 0, 0);
  STAGE(0, 0, 1, 1); STAGE(1, 0, 1, 1);
  asm volatile("s_waitcnt vmcnt(4)" ::: "memory");
  BAR;

  for (int t = 0; t < NT; ++t){
    const int pb = t & 1, qb = pb ^ 1;
    const bool s1 = (t + 1 < NT), s2 = (t + 2 < NT);
    PHASE(0, 0, if (s1) STAGE(0, 1, t + 1, qb), );   // stage A1(t+1)
    PHASE(0, 1, if (s1) STAGE(1, 1, t + 1, qb), );   // stage B1(t+1)
    PHASE(1, 0, if (s2) STAGE(0, 0, t + 2, pb), );   // stage A0(t+2)
    PHASE(1, 1, if (s2) STAGE(1, 0, t + 2, pb),      // stage B0(t+2) + wait
          if (s2) { asm volatile("s_waitcnt vmcnt(4)" ::: "memory"); }
          else    { asm volatile("s_waitcnt vmcnt(0)" ::: "memory"); });
  }
#undef PHASE
#undef LDSRD
#undef STAGE

  // epilogue: +bias, cast bf16, store. C/D: col=lane&15, row=4*(lane>>4)+r
  #pragma unroll
  for (int qn = 0; qn < 2; ++qn)
    #pragma unroll
    for (int j = 0; j < 2; ++j){
      const int col = n0 + (qn << 7) + (wc << 5) + (j << 4) + lr;
      const float bj = bias[col];
      #pragma unroll
      for (int qm = 0; qm < 2; ++qm)
        #pragma unroll
        for (int i = 0; i < 4; ++i){
          const int row0 = m0 + (qm << 7) + (wr << 6) + (i << 4) + (hi << 2);
          #pragma unroll
          for (int r = 0; r < 4; ++r)
            Cg[(size_t)(row0 + r) * NQ + col] = f2bf(acc[qm][qn][i][j][r] + bj);
        }
    }
#undef BAR
#undef FENCE
}

// ---------------- scan phase 1: per-chunk aggregates (P = prod a, Q) ---------
__global__ __launch_bounds__(256) void scan1(const u16* __restrict__ gh,
                                             float* __restrict__ P,
                                             float* __restrict__ Q){
  const int b = blockIdx.x >> 6;     // CCH=64
  const int c = blockIdx.x & 63;
  const int d4 = threadIdx.x << 2;
  const u16* base = gh + ((size_t)(b * SQ + c * TCH) * NQ) + d4;
  float p[4] = {1.f,1.f,1.f,1.f}, q[4] = {0.f,0.f,0.f,0.f};
  for (int t = 0; t < TCH; ++t){
    u16x4 gv = *(const u16x4*)(base + (size_t)t * NQ);
    u16x4 hv = *(const u16x4*)(base + (size_t)t * NQ + DQ);
    #pragma unroll
    for (int e = 0; e < 4; ++e){
      float a, bv; sig_ab(bf2f(gv[e]), bf2f(hv[e]), a, bv);
      p[e] *= a; q[e] = a * q[e] + bv;
    }
  }
  const size_t o = ((size_t)blockIdx.x << 10) + d4;
  *(f32x4*)(P + o) = f32x4{p[0], p[1], p[2], p[3]};
  *(f32x4*)(Q + o) = f32x4{q[0], q[1], q[2], q[3]};
}

// ---------------- scan phase 2: scan across chunks; also emits h_last --------
__global__ __launch_bounds__(256) void scan2(const float* __restrict__ P,
                                             const float* __restrict__ Q,
                                             float* __restrict__ hst,
                                             float* __restrict__ hlast){
  const int idx = blockIdx.x * 256 + threadIdx.x;   // 0..B*D-1
  const int b = idx >> 10, d = idx & 1023;
  float h = 0.5f;                                   // h0 = g(0) = 0.5
  for (int c = 0; c < CCH; ++c){
    const size_t o = ((size_t)(b * CCH + c) << 10) + d;
    hst[o] = h;
    h = P[o] * h + Q[o];
  }
  hlast[idx] = h;
}

// ---------------- scan phase 3: replay within chunk, h + residual ------------
__global__ __launch_bounds__(256) void scan3(const u16* __restrict__ gh,
                                             const float* __restrict__ hst,
                                             const float* __restrict__ inp,
                                             float* __restrict__ outp){
  const int b = blockIdx.x >> 6;
  const int c = blockIdx.x & 63;
  const int d4 = threadIdx.x << 2;
  const size_t srow = (size_t)(b * SQ + c * TCH);
  const u16*   base = gh   + srow * NQ + d4;
  const float* ib   = inp  + srow * DQ + d4;
  float*       ob   = outp + srow * DQ + d4;
  const size_t o = ((size_t)blockIdx.x << 10) + d4;
  f32x4 h0 = *(const f32x4*)(hst + o);
  float h[4] = {h0[0], h0[1], h0[2], h0[3]};
  for (int t = 0; t < TCH; ++t){
    u16x4 gv = *(const u16x4*)(base + (size_t)t * NQ);
    u16x4 hh = *(const u16x4*)(base + (size_t)t * NQ + DQ);
    f32x4 iv = *(const f32x4*)(ib + (size_t)t * DQ);
    f32x4 ov;
    #pragma unroll
    for (int e = 0; e < 4; ++e){
      float a, bv; sig_ab(bf2f(gv[e]), bf2f(hh[e]), a, bv);
      h[e] = a * h[e] + bv;
      ov[e] = h[e] + iv[e];
    }
    *(f32x4*)(ob + (size_t)t * DQ) = ov;
  }
}

extern "C" void kernel_launch(void* const* d_in, const int* in_sizes, int n_in,
                              void* d_out, int out_size, void* d_ws, size_t ws_size,
                              hipStream_t stream) {
  const float* x     = (const float*)d_in[0];   // (8,4096,1024)
  const float* gamma = (const float*)d_in[1];   // (3,1024)
  const float* beta  = (const float*)d_in[2];   // (3,1024)
  const float* W     = (const float*)d_in[3];   // (3,1024,2048)
  const float* bias  = (const float*)d_in[4];   // (3,2048)
  float* out = (float*)d_out;                   // 33554432 + 3*8192 floats

  char* ws = (char*)d_ws;
  const size_t ACT = (size_t)MQ * DQ * 4;                 // 128 MiB
  float* bufA = (float*)(ws);
  float* bufB = (float*)(ws + ACT);
  u16*   gh   = (u16*)  (ws + 2 * ACT);                   // MQ*NQ bf16 = 128 MiB
  u16*   xn   = (u16*)  (ws + 3 * ACT);                   // MQ*DQ bf16 = 64 MiB
  u16*   WT   = (u16*)  (ws + 3 * ACT + (size_t)MQ * DQ * 2);
  float* Pa   = (float*)(ws + 3 * ACT + (size_t)MQ * DQ * 2 + (size_t)3 * NQ * KQ * 2);
  float* Qa   = Pa + (size_t)BQ * CCH * DQ;
  float* hst  = Qa + (size_t)BQ * CCH * DQ;

  wt_cast<<<dim3(KQ / 64, NQ / 64, 3), 256, 0, stream>>>(W, WT);

  const float* inp = x;
  for (int l = 0; l < 3; ++l){
    ln_cast<<<MQ, 256, 0, stream>>>(inp, gamma + l * DQ, beta + l * DQ, xn);
    gemm_k8<<<dim3((NQ / 256) * (MQ / 256)), 512, 0, stream>>>(
        xn, WT + (size_t)l * NQ * KQ, bias + l * NQ, gh);
    scan1<<<BQ * CCH, 256, 0, stream>>>(gh, Pa, Qa);
    scan2<<<(BQ * DQ) / 256, 256, 0, stream>>>(Pa, Qa, hst, out + (size_t)MQ * DQ + l * BQ * DQ);
    float* o = (l == 2) ? out : (l == 0 ? bufA : bufB);
    scan3<<<BQ * CCH, 256, 0, stream>>>(gh, hst, inp, o);
    inp = o;
  }
}

// Round 4
// 865.977 us; speedup vs baseline: 1.2267x; 1.0450x over previous
//
#include <hip/hip_runtime.h>

typedef unsigned short u16;
typedef unsigned int   u32;
typedef float  f32x4  __attribute__((ext_vector_type(4)));
typedef short  bf16x8 __attribute__((ext_vector_type(8)));
typedef u16    u16x4  __attribute__((ext_vector_type(4)));

#define BQ 8
#define SQ 4096
#define DQ 1024
#define NQ 2048      // 2*D
#define MQ 32768     // B*S
#define KQ 1024
#define CCH 64       // chunks per sequence
#define TCH 64       // timesteps per chunk (CCH*TCH == SQ)
#define NT 16        // K-tiles (KQ/64)

__device__ __forceinline__ float bf2f(u16 u){
  union { u32 i; float f; } v; v.i = ((u32)u) << 16; return v.f;
}
__device__ __forceinline__ u16 f2bf(float f){
  union { float f; u32 i; } v; v.f = f;
  u32 r = v.i + 0x7fffu + ((v.i >> 16) & 1u);   // round-to-nearest-even
  return (u16)(r >> 16);
}

// a = 1 - sigmoid(gate) = sigmoid(-gate);  bv = sigmoid(gate) * g(hidden)
__device__ __forceinline__ void sig_ab(float gate, float hid, float& a, float& bv){
  float eg = __expf(gate);
  float a_ = __builtin_amdgcn_rcpf(1.f + eg);
  float z  = 1.f - a_;
  float eh = __expf(hid);
  float sg = eh * __builtin_amdgcn_rcpf(1.f + eh);
  float gval = (hid >= 0.f) ? (hid + 0.5f) : sg;
  a = a_; bv = z * gval;
}

__device__ __forceinline__ void gload_lds16(const u16* g, u16* l){
  __builtin_amdgcn_global_load_lds(
      (const __attribute__((address_space(1))) u32*)g,
      (__attribute__((address_space(3)))       u32*)l,
      16, 0, 0);
}

// ---------------- W transpose + bf16 cast: [L][K][N] f32 -> [L][N][K] bf16 ----
__global__ __launch_bounds__(256) void wt_cast(const float* __restrict__ W,
                                               u16* __restrict__ WT){
  __shared__ float t[64][65];
  const int l  = blockIdx.z;
  const int k0 = blockIdx.x << 6, n0 = blockIdx.y << 6;
  const float* Wl = W  + (size_t)l * KQ * NQ;
  u16*         Tl = WT + (size_t)l * NQ * KQ;
  const int c = threadIdx.x & 63, r4 = threadIdx.x >> 6;
  #pragma unroll
  for (int i = 0; i < 16; ++i){
    int r = i * 4 + r4;
    t[r][c] = Wl[(size_t)(k0 + r) * NQ + n0 + c];
  }
  __syncthreads();
  #pragma unroll
  for (int i = 0; i < 16; ++i){
    int r = i * 4 + r4;
    Tl[(size_t)(n0 + r) * KQ + k0 + c] = f2bf(t[c][r]);
  }
}

// ---------------- LayerNorm (fp32 in) + bf16 cast -----------------------------
__global__ __launch_bounds__(256) void ln_cast(const float* __restrict__ x,
                                               const float* __restrict__ gamma,
                                               const float* __restrict__ beta,
                                               u16* __restrict__ xn){
  const size_t row = blockIdx.x;
  const int tid = threadIdx.x;
  f32x4 xv = *(const f32x4*)(x + row * DQ + tid * 4);
  float s  = xv[0] + xv[1] + xv[2] + xv[3];
  float s2 = xv[0]*xv[0] + xv[1]*xv[1] + xv[2]*xv[2] + xv[3]*xv[3];
  #pragma unroll
  for (int off = 32; off > 0; off >>= 1){
    s  += __shfl_down(s,  off);
    s2 += __shfl_down(s2, off);
  }
  __shared__ float red[8];
  const int wave = tid >> 6, lane = tid & 63;
  if (lane == 0){ red[wave] = s; red[4 + wave] = s2; }
  __syncthreads();
  s  = red[0] + red[1] + red[2] + red[3];
  s2 = red[4] + red[5] + red[6] + red[7];
  const float mean = s * (1.f / DQ);
  float var = fmaxf(s2 * (1.f / DQ) - mean * mean, 0.f);
  const float rstd = rsqrtf(var + 1e-5f);
  f32x4 gv = *(const f32x4*)(gamma + tid * 4);
  f32x4 bv = *(const f32x4*)(beta  + tid * 4);
  u16x4 o;
  #pragma unroll
  for (int e = 0; e < 4; ++e) o[e] = f2bf((xv[e] - mean) * rstd * gv[e] + bv[e]);
  *(u16x4*)(xn + row * DQ + tid * 4) = o;
}

// ---------------- GEMM: 256x256 tile, BK=64, 8 waves, reg-reuse 4-phase ------
// A: [M][K] bf16 row-major, Bt: [N][K] bf16 row-major (= W^T).
// LDS: [buf][op A/B][half 128-rows][128][64] bf16, st-swizzled (slot ^= row&7),
// staged via global_load_lds with pre-swizzled global source (rule #21).
// R4 change (vs R3): operand fragments persist in registers across phases —
// P1 reads A0+B0 (12 ds_read_b128), P2 reads B1 (4), P3 reads A1 (8),
// P4 reads nothing. 24 reads/K-tile vs 48 — halves LDS-read-pipe time,
// which R3 counters showed was the limiter (MfmaUtil 35%, conflicts 0).
// Stage stream per tile t: A1(t+1)@P1, B1(t+1)@P2, A0(t+2)@P3, B0(t+2)@P4.
// WAR re-derived: every staged slot's last reader is an earlier barrier-
// separated phase. vmcnt(4) once/tile; vmcnt(0) at t==NT-2 (tail drain).
__global__ __launch_bounds__(512, 2) void gemm_k8(const u16* __restrict__ A,
                                                  const u16* __restrict__ Bt,
                                                  const float* __restrict__ bias,
                                                  u16* __restrict__ Cg){
  __shared__ u16 lds[2][2][2][8192];   // [buf][op][half][row*64+col] = 128 KiB
  const int bid = blockIdx.x;
  const int swz = ((bid & 7) << 7) | (bid >> 3);   // 1024 wgs, %8==0 -> bijective
  const int bn = swz & 7, bm = swz >> 3;           // XCD owns contiguous bm stripe
  const int n0 = bn << 8, m0 = bm << 8;
  const int tid = threadIdx.x;
  const int w = tid >> 6, lane = tid & 63;
  const int wr = w >> 2, wc = w & 3;               // 2M x 4N wave grid
  const int lr = lane & 15, hi = lane >> 4;
  const int sl8 = lane >> 3;                       // staging row-in-8 (== row&7)
  const int sslot = (lane & 7) ^ sl8;              // pre-swizzled global slot

  f32x4 acc[2][2][4][2] = {};                      // [qm][qn][i][j]
  bf16x8 afr[4][2];                                // current A half (32 VGPR)
  bf16x8 bf0[2][2], bf1[2][2];                     // both B halves (16+16 VGPR)

#define FENCE asm volatile("" ::: "memory")
#define BAR do { FENCE; __builtin_amdgcn_s_barrier(); FENCE; } while(0)

#define STAGE(op, hf, kt, pb_) do {                                             \
    const u16* gsrc_ = (op) ? Bt : A;                                           \
    const int rb_ = ((op) ? n0 : m0) + ((hf) << 7);                             \
    _Pragma("unroll")                                                           \
    for (int g_ = 0; g_ < 2; ++g_){                                             \
      const int row_ = (w << 4) + (g_ << 3) + sl8;                              \
      gload_lds16(gsrc_ + (size_t)(rb_ + row_) * KQ + ((kt) << 6) + (sslot << 3),\
                  &lds[pb_][op][hf][((w << 4) + (g_ << 3)) << 6]);              \
    }                                                                           \
  } while(0)

  // swizzled ds_read: logical (row, 16B-slot) -> byte row*128 + (slot^(row&7))*16
#define LDSRD(dst, base_, row_, slot_) do {                                     \
    const int r_ = (row_);                                                      \
    dst = *(const bf16x8*)((const char*)(base_) +                               \
          ((r_ << 7) + ((((slot_)) ^ (r_ & 7)) << 4)));                         \
  } while(0)

#define RD_A(hf) do {                                                           \
    const u16* Ah_ = &lds[pb][0][hf][0];                                        \
    _Pragma("unroll")                                                           \
    for (int i_ = 0; i_ < 4; ++i_)                                              \
      _Pragma("unroll")                                                         \
      for (int kk_ = 0; kk_ < 2; ++kk_)                                         \
        LDSRD(afr[i_][kk_], Ah_, (wr << 6) + (i_ << 4) + lr, (kk_ << 2) + hi);  \
  } while(0)

#define RD_B(dst, hf) do {                                                      \
    const u16* Bh_ = &lds[pb][1][hf][0];                                        \
    _Pragma("unroll")                                                           \
    for (int j_ = 0; j_ < 2; ++j_)                                              \
      _Pragma("unroll")                                                         \
      for (int kk_ = 0; kk_ < 2; ++kk_)                                         \
        LDSRD(dst[j_][kk_], Bh_, (wc << 5) + (j_ << 4) + lr, (kk_ << 2) + hi);  \
  } while(0)

#define MM(qm, qn, B) do {                                                      \
    _Pragma("unroll")                                                           \
    for (int i_ = 0; i_ < 4; ++i_)                                              \
      _Pragma("unroll")                                                         \
      for (int j_ = 0; j_ < 2; ++j_)                                            \
        _Pragma("unroll")                                                       \
        for (int kk_ = 0; kk_ < 2; ++kk_)                                       \
          acc[qm][qn][i_][j_] = __builtin_amdgcn_mfma_f32_16x16x32_bf16(        \
              afr[i_][kk_], B[j_][kk_], acc[qm][qn][i_][j_], 0, 0, 0);          \
  } while(0)

#define PH(RDS, STG, MFMAS, VMW) do {                                           \
    RDS;                                                                        \
    STG;                                                                        \
    BAR;                                                                        \
    asm volatile("s_waitcnt lgkmcnt(0)" ::: "memory");                          \
    __builtin_amdgcn_s_setprio(1);                                              \
    MFMAS;                                                                      \
    __builtin_amdgcn_s_setprio(0);                                              \
    VMW;                                                                        \
    BAR;                                                                        \
  } while(0)

  // prologue: tile0 all 4 halves + tile1 {A0,B0}; vmcnt(4) = tile0 landed
  STAGE(0, 0, 0, 0); STAGE(0, 1, 0, 0); STAGE(1, 0, 0, 0); STAGE(1, 1, 0, 0);
  STAGE(0, 0, 1, 1); STAGE(1, 0, 1, 1);
  asm volatile("s_waitcnt vmcnt(4)" ::: "memory");
  BAR;

  for (int t = 0; t < NT; ++t){
    const int pb = t & 1, qb = pb ^ 1;
    const bool s1 = (t + 1 < NT), s2 = (t + 2 < NT);
    PH(RD_A(0); RD_B(bf0, 0), if (s1) STAGE(0, 1, t + 1, qb), MM(0, 0, bf0), );
    PH(RD_B(bf1, 1),          if (s1) STAGE(1, 1, t + 1, qb), MM(0, 1, bf1), );
    PH(RD_A(1),               if (s2) STAGE(0, 0, t + 2, pb), MM(1, 0, bf0), );
    PH(,                      if (s2) STAGE(1, 0, t + 2, pb), MM(1, 1, bf1),
       if (s2) { asm volatile("s_waitcnt vmcnt(4)" ::: "memory"); }
       else    { asm volatile("s_waitcnt vmcnt(0)" ::: "memory"); });
  }
#undef PH
#undef MM
#undef RD_B
#undef RD_A
#undef LDSRD
#undef STAGE

  // epilogue: +bias, cast bf16, store. C/D: col=lane&15, row=4*(lane>>4)+r
  #pragma unroll
  for (int qn = 0; qn < 2; ++qn)
    #pragma unroll
    for (int j = 0; j < 2; ++j){
      const int col = n0 + (qn << 7) + (wc << 5) + (j << 4) + lr;
      const float bj = bias[col];
      #pragma unroll
      for (int qm = 0; qm < 2; ++qm)
        #pragma unroll
        for (int i = 0; i < 4; ++i){
          const int row0 = m0 + (qm << 7) + (wr << 6) + (i << 4) + (hi << 2);
          #pragma unroll
          for (int r = 0; r < 4; ++r)
            Cg[(size_t)(row0 + r) * NQ + col] = f2bf(acc[qm][qn][i][j][r] + bj);
        }
    }
#undef BAR
#undef FENCE
}

// ---------------- scan phase 1: per-chunk aggregates (P = prod a, Q) ---------
__global__ __launch_bounds__(256) void scan1(const u16* __restrict__ gh,
                                             float* __restrict__ P,
                                             float* __restrict__ Q){
  const int b = blockIdx.x >> 6;     // CCH=64
  const int c = blockIdx.x & 63;
  const int d4 = threadIdx.x << 2;
  const u16* base = gh + ((size_t)(b * SQ + c * TCH) * NQ) + d4;
  float p[4] = {1.f,1.f,1.f,1.f}, q[4] = {0.f,0.f,0.f,0.f};
  for (int t = 0; t < TCH; ++t){
    u16x4 gv = *(const u16x4*)(base + (size_t)t * NQ);
    u16x4 hv = *(const u16x4*)(base + (size_t)t * NQ + DQ);
    #pragma unroll
    for (int e = 0; e < 4; ++e){
      float a, bv; sig_ab(bf2f(gv[e]), bf2f(hv[e]), a, bv);
      p[e] *= a; q[e] = a * q[e] + bv;
    }
  }
  const size_t o = ((size_t)blockIdx.x << 10) + d4;
  *(f32x4*)(P + o) = f32x4{p[0], p[1], p[2], p[3]};
  *(f32x4*)(Q + o) = f32x4{q[0], q[1], q[2], q[3]};
}

// ---------------- scan phase 2: scan across chunks; also emits h_last --------
__global__ __launch_bounds__(256) void scan2(const float* __restrict__ P,
                                             const float* __restrict__ Q,
                                             float* __restrict__ hst,
                                             float* __restrict__ hlast){
  const int idx = blockIdx.x * 256 + threadIdx.x;   // 0..B*D-1
  const int b = idx >> 10, d = idx & 1023;
  float h = 0.5f;                                   // h0 = g(0) = 0.5
  for (int c = 0; c < CCH; ++c){
    const size_t o = ((size_t)(b * CCH + c) << 10) + d;
    hst[o] = h;
    h = P[o] * h + Q[o];
  }
  hlast[idx] = h;
}

// ---------------- scan phase 3: replay within chunk, h + residual ------------
__global__ __launch_bounds__(256) void scan3(const u16* __restrict__ gh,
                                             const float* __restrict__ hst,
                                             const float* __restrict__ inp,
                                             float* __restrict__ outp){
  const int b = blockIdx.x >> 6;
  const int c = blockIdx.x & 63;
  const int d4 = threadIdx.x << 2;
  const size_t srow = (size_t)(b * SQ + c * TCH);
  const u16*   base = gh   + srow * NQ + d4;
  const float* ib   = inp  + srow * DQ + d4;
  float*       ob   = outp + srow * DQ + d4;
  const size_t o = ((size_t)blockIdx.x << 10) + d4;
  f32x4 h0 = *(const f32x4*)(hst + o);
  float h[4] = {h0[0], h0[1], h0[2], h0[3]};
  for (int t = 0; t < TCH; ++t){
    u16x4 gv = *(const u16x4*)(base + (size_t)t * NQ);
    u16x4 hh = *(const u16x4*)(base + (size_t)t * NQ + DQ);
    f32x4 iv = *(const f32x4*)(ib + (size_t)t * DQ);
    f32x4 ov;
    #pragma unroll
    for (int e = 0; e < 4; ++e){
      float a, bv; sig_ab(bf2f(gv[e]), bf2f(hh[e]), a, bv);
      h[e] = a * h[e] + bv;
      ov[e] = h[e] + iv[e];
    }
    *(f32x4*)(ob + (size_t)t * DQ) = ov;
  }
}

extern "C" void kernel_launch(void* const* d_in, const int* in_sizes, int n_in,
                              void* d_out, int out_size, void* d_ws, size_t ws_size,
                              hipStream_t stream) {
  const float* x     = (const float*)d_in[0];   // (8,4096,1024)
  const float* gamma = (const float*)d_in[1];   // (3,1024)
  const float* beta  = (const float*)d_in[2];   // (3,1024)
  const float* W     = (const float*)d_in[3];   // (3,1024,2048)
  const float* bias  = (const float*)d_in[4];   // (3,2048)
  float* out = (float*)d_out;                   // 33554432 + 3*8192 floats

  char* ws = (char*)d_ws;
  const size_t ACT = (size_t)MQ * DQ * 4;                 // 128 MiB
  float* bufA = (float*)(ws);
  float* bufB = (float*)(ws + ACT);
  u16*   gh   = (u16*)  (ws + 2 * ACT);                   // MQ*NQ bf16 = 128 MiB
  u16*   xn   = (u16*)  (ws + 3 * ACT);                   // MQ*DQ bf16 = 64 MiB
  u16*   WT   = (u16*)  (ws + 3 * ACT + (size_t)MQ * DQ * 2);
  float* Pa   = (float*)(ws + 3 * ACT + (size_t)MQ * DQ * 2 + (size_t)3 * NQ * KQ * 2);
  float* Qa   = Pa + (size_t)BQ * CCH * DQ;
  float* hst  = Qa + (size_t)BQ * CCH * DQ;

  wt_cast<<<dim3(KQ / 64, NQ / 64, 3), 256, 0, stream>>>(W, WT);

  const float* inp = x;
  for (int l = 0; l < 3; ++l){
    ln_cast<<<MQ, 256, 0, stream>>>(inp, gamma + l * DQ, beta + l * DQ, xn);
    gemm_k8<<<dim3((NQ / 256) * (MQ / 256)), 512, 0, stream>>>(
        xn, WT + (size_t)l * NQ * KQ, bias + l * NQ, gh);
    scan1<<<BQ * CCH, 256, 0, stream>>>(gh, Pa, Qa);
    scan2<<<(BQ * DQ) / 256, 256, 0, stream>>>(Pa, Qa, hst, out + (size_t)MQ * DQ + l * BQ * DQ);
    float* o = (l == 2) ? out : (l == 0 ? bufA : bufB);
    scan3<<<BQ * CCH, 256, 0, stream>>>(gh, hst, inp, o);
    inp = o;
  }
}

// Round 5
// 814.451 us; speedup vs baseline: 1.3043x; 1.0633x over previous
//
#include <hip/hip_runtime.h>

typedef unsigned short u16;
typedef unsigned int   u32;
typedef float  f32x4  __attribute__((ext_vector_type(4)));
typedef short  bf16x8 __attribute__((ext_vector_type(8)));
typedef u16    u16x4  __attribute__((ext_vector_type(4)));

#define BQ 8
#define SQ 4096
#define DQ 1024
#define NQ 2048      // 2*D
#define MQ 32768     // B*S
#define KQ 1024
#define CCH 64       // chunks per sequence
#define TCH 64       // timesteps per chunk (CCH*TCH == SQ)
#define NT 16        // K-tiles (KQ/64)

__device__ __forceinline__ float bf2f(u16 u){
  union { u32 i; float f; } v; v.i = ((u32)u) << 16; return v.f;
}
__device__ __forceinline__ u16 f2bf(float f){
  union { float f; u32 i; } v; v.f = f;
  u32 r = v.i + 0x7fffu + ((v.i >> 16) & 1u);   // round-to-nearest-even
  return (u16)(r >> 16);
}

// a = 1 - sigmoid(gate) = sigmoid(-gate);  bv = sigmoid(gate) * g(hidden)
__device__ __forceinline__ void sig_ab(float gate, float hid, float& a, float& bv){
  float eg = __expf(gate);
  float a_ = __builtin_amdgcn_rcpf(1.f + eg);
  float z  = 1.f - a_;
  float eh = __expf(hid);
  float sg = eh * __builtin_amdgcn_rcpf(1.f + eh);
  float gval = (hid >= 0.f) ? (hid + 0.5f) : sg;
  a = a_; bv = z * gval;
}

__device__ __forceinline__ void gload_lds16(const u16* g, u16* l){
  __builtin_amdgcn_global_load_lds(
      (const __attribute__((address_space(1))) u32*)g,
      (__attribute__((address_space(3)))       u32*)l,
      16, 0, 0);
}

// ---------------- W transpose + bf16 cast: [L][K][N] f32 -> [L][N][K] bf16 ----
__global__ __launch_bounds__(256) void wt_cast(const float* __restrict__ W,
                                               u16* __restrict__ WT){
  __shared__ float t[64][65];
  const int l  = blockIdx.z;
  const int k0 = blockIdx.x << 6, n0 = blockIdx.y << 6;
  const float* Wl = W  + (size_t)l * KQ * NQ;
  u16*         Tl = WT + (size_t)l * NQ * KQ;
  const int c = threadIdx.x & 63, r4 = threadIdx.x >> 6;
  #pragma unroll
  for (int i = 0; i < 16; ++i){
    int r = i * 4 + r4;
    t[r][c] = Wl[(size_t)(k0 + r) * NQ + n0 + c];
  }
  __syncthreads();
  #pragma unroll
  for (int i = 0; i < 16; ++i){
    int r = i * 4 + r4;
    Tl[(size_t)(n0 + r) * KQ + k0 + c] = f2bf(t[c][r]);
  }
}

// ---------------- LayerNorm (fp32 in) + bf16 cast — layer 0 only -------------
__global__ __launch_bounds__(256) void ln_cast(const float* __restrict__ x,
                                               const float* __restrict__ gamma,
                                               const float* __restrict__ beta,
                                               u16* __restrict__ xn){
  const size_t row = blockIdx.x;
  const int tid = threadIdx.x;
  f32x4 xv = *(const f32x4*)(x + row * DQ + tid * 4);
  float s  = xv[0] + xv[1] + xv[2] + xv[3];
  float s2 = xv[0]*xv[0] + xv[1]*xv[1] + xv[2]*xv[2] + xv[3]*xv[3];
  #pragma unroll
  for (int off = 32; off > 0; off >>= 1){
    s  += __shfl_down(s,  off);
    s2 += __shfl_down(s2, off);
  }
  __shared__ float red[8];
  const int wave = tid >> 6, lane = tid & 63;
  if (lane == 0){ red[wave] = s; red[4 + wave] = s2; }
  __syncthreads();
  s  = red[0] + red[1] + red[2] + red[3];
  s2 = red[4] + red[5] + red[6] + red[7];
  const float mean = s * (1.f / DQ);
  float var = fmaxf(s2 * (1.f / DQ) - mean * mean, 0.f);
  const float rstd = rsqrtf(var + 1e-5f);
  f32x4 gv = *(const f32x4*)(gamma + tid * 4);
  f32x4 bv = *(const f32x4*)(beta  + tid * 4);
  u16x4 o;
  #pragma unroll
  for (int e = 0; e < 4; ++e) o[e] = f2bf((xv[e] - mean) * rstd * gv[e] + bv[e]);
  *(u16x4*)(xn + row * DQ + tid * 4) = o;
}

// ---------------- GEMM: 256x256 tile, BK=64, 8 waves, 1-barrier phases -------
// R5 restructure (sync ledger re-derived; R4 counters showed ~3.1k cyc/K-tile
// of sync stall from 8 barriers/tile + short-lead vmcnt(4)):
//  * ALL 4 stages of tile t+1 issued during tile t, into buf[qb] (opposite
//    buffer) — stages and reads NEVER share a buffer, so intra-tile WAR is
//    structural; each staged region's last reader is tile t-1 (>=4 barriers).
//  * ONE barrier per phase (4/tile): phase = {vmcnt(N); BAR; stage; ds_reads;
//    lgkmcnt(0); setprio; 16 MFMA; setprio}.
//  * Per-phase counted vmcnt with 3-phase lead. Steady state (issue order
//    B0,A0,B1,A1 per tile): P1 vmcnt(4) [drain B0,A0(t), keep B1,A1(t)];
//    P2 vmcnt(4) [drain B1(t), keep A1(t),B0(t+1)]; P3 vmcnt(4) [drain A1(t)];
//    P4 none. Tail t=NT-1 (no new stages in flight): P2 vmcnt(2), P3 vmcnt(0).
//  * Fragments persist in regs across phases (R4): reads 12/4/8/0 per phase.
__global__ __launch_bounds__(512, 2) void gemm_k8(const u16* __restrict__ A,
                                                  const u16* __restrict__ Bt,
                                                  const float* __restrict__ bias,
                                                  u16* __restrict__ Cg){
  __shared__ u16 lds[2][2][2][8192];   // [buf][op][half][row*64+col] = 128 KiB
  const int bid = blockIdx.x;
  const int swz = ((bid & 7) << 7) | (bid >> 3);   // 1024 wgs, %8==0 -> bijective
  const int bn = swz & 7, bm = swz >> 3;           // XCD owns contiguous bm stripe
  const int n0 = bn << 8, m0 = bm << 8;
  const int tid = threadIdx.x;
  const int w = tid >> 6, lane = tid & 63;
  const int wr = w >> 2, wc = w & 3;               // 2M x 4N wave grid
  const int lr = lane & 15, hi = lane >> 4;
  const int sl8 = lane >> 3;                       // staging row-in-8 (== row&7)
  const int sslot = (lane & 7) ^ sl8;              // pre-swizzled global slot

  f32x4 acc[2][2][4][2] = {};                      // [qm][qn][i][j]
  bf16x8 afr[4][2];                                // current A half (32 VGPR)
  bf16x8 bf0[2][2], bf1[2][2];                     // both B halves (16+16 VGPR)

#define FENCE asm volatile("" ::: "memory")
#define BAR do { FENCE; __builtin_amdgcn_s_barrier(); FENCE; } while(0)

#define STAGE(op, hf, kt, pb_) do {                                             \
    const u16* gsrc_ = (op) ? Bt : A;                                           \
    const int rb_ = ((op) ? n0 : m0) + ((hf) << 7);                             \
    _Pragma("unroll")                                                           \
    for (int g_ = 0; g_ < 2; ++g_){                                             \
      const int row_ = (w << 4) + (g_ << 3) + sl8;                              \
      gload_lds16(gsrc_ + (size_t)(rb_ + row_) * KQ + ((kt) << 6) + (sslot << 3),\
                  &lds[pb_][op][hf][((w << 4) + (g_ << 3)) << 6]);              \
    }                                                                           \
  } while(0)

  // swizzled ds_read: logical (row, 16B-slot) -> byte row*128 + (slot^(row&7))*16
#define LDSRD(dst, base_, row_, slot_) do {                                     \
    const int r_ = (row_);                                                      \
    dst = *(const bf16x8*)((const char*)(base_) +                               \
          ((r_ << 7) + ((((slot_)) ^ (r_ & 7)) << 4)));                         \
  } while(0)

#define RD_A(hf) do {                                                           \
    const u16* Ah_ = &lds[pb][0][hf][0];                                        \
    _Pragma("unroll")                                                           \
    for (int i_ = 0; i_ < 4; ++i_)                                              \
      _Pragma("unroll")                                                         \
      for (int kk_ = 0; kk_ < 2; ++kk_)                                         \
        LDSRD(afr[i_][kk_], Ah_, (wr << 6) + (i_ << 4) + lr, (kk_ << 2) + hi);  \
  } while(0)

#define RD_B(dst, hf) do {                                                      \
    const u16* Bh_ = &lds[pb][1][hf][0];                                        \
    _Pragma("unroll")                                                           \
    for (int j_ = 0; j_ < 2; ++j_)                                              \
      _Pragma("unroll")                                                         \
      for (int kk_ = 0; kk_ < 2; ++kk_)                                         \
        LDSRD(dst[j_][kk_], Bh_, (wc << 5) + (j_ << 4) + lr, (kk_ << 2) + hi);  \
  } while(0)

#define MM(qm, qn, B) do {                                                      \
    _Pragma("unroll")                                                           \
    for (int i_ = 0; i_ < 4; ++i_)                                              \
      _Pragma("unroll")                                                         \
      for (int j_ = 0; j_ < 2; ++j_)                                            \
        _Pragma("unroll")                                                       \
        for (int kk_ = 0; kk_ < 2; ++kk_)                                       \
          acc[qm][qn][i_][j_] = __builtin_amdgcn_mfma_f32_16x16x32_bf16(        \
              afr[i_][kk_], B[j_][kk_], acc[qm][qn][i_][j_], 0, 0, 0);          \
  } while(0)

#define PH(VMW, STG, RDS, MFMAS) do {                                           \
    VMW;                                                                        \
    BAR;                                                                        \
    STG;                                                                        \
    RDS;                                                                        \
    asm volatile("s_waitcnt lgkmcnt(0)" ::: "memory");                          \
    __builtin_amdgcn_s_setprio(1);                                              \
    MFMAS;                                                                      \
    __builtin_amdgcn_s_setprio(0);                                              \
  } while(0)

  // prologue: stage tile0 into buf0, issue order B0,A0,B1,A1 (= steady state)
  STAGE(1, 0, 0, 0); STAGE(0, 0, 0, 0); STAGE(1, 1, 0, 0); STAGE(0, 1, 0, 0);

  for (int t = 0; t < NT; ++t){
    const int pb = t & 1, qb = pb ^ 1;
    const bool s = (t + 1 < NT);
    PH(asm volatile("s_waitcnt vmcnt(4)" ::: "memory"),
       if (s) STAGE(1, 0, t + 1, qb),                 // B0(t+1)
       RD_A(0); RD_B(bf0, 0),
       MM(0, 0, bf0));
    PH(if (s) { asm volatile("s_waitcnt vmcnt(4)" ::: "memory"); }
       else   { asm volatile("s_waitcnt vmcnt(2)" ::: "memory"); },
       if (s) STAGE(0, 0, t + 1, qb),                 // A0(t+1)
       RD_B(bf1, 1),
       MM(0, 1, bf1));
    PH(if (s) { asm volatile("s_waitcnt vmcnt(4)" ::: "memory"); }
       else   { asm volatile("s_waitcnt vmcnt(0)" ::: "memory"); },
       if (s) STAGE(1, 1, t + 1, qb),                 // B1(t+1)
       RD_A(1),
       MM(1, 0, bf0));
    PH(,
       if (s) STAGE(0, 1, t + 1, qb),                 // A1(t+1)
       ,
       MM(1, 1, bf1));
  }
#undef PH
#undef MM
#undef RD_B
#undef RD_A
#undef LDSRD
#undef STAGE

  // epilogue: +bias, cast bf16, store. C/D: col=lane&15, row=4*(lane>>4)+r
  #pragma unroll
  for (int qn = 0; qn < 2; ++qn)
    #pragma unroll
    for (int j = 0; j < 2; ++j){
      const int col = n0 + (qn << 7) + (wc << 5) + (j << 4) + lr;
      const float bj = bias[col];
      #pragma unroll
      for (int qm = 0; qm < 2; ++qm)
        #pragma unroll
        for (int i = 0; i < 4; ++i){
          const int row0 = m0 + (qm << 7) + (wr << 6) + (i << 4) + (hi << 2);
          #pragma unroll
          for (int r = 0; r < 4; ++r)
            Cg[(size_t)(row0 + r) * NQ + col] = f2bf(acc[qm][qn][i][j][r] + bj);
        }
    }
#undef BAR
#undef FENCE
}

// ---------------- scan phase 1: per-chunk aggregates (P = prod a, Q) ---------
__global__ __launch_bounds__(256) void scan1(const u16* __restrict__ gh,
                                             float* __restrict__ P,
                                             float* __restrict__ Q){
  const int b = blockIdx.x >> 6;     // CCH=64
  const int c = blockIdx.x & 63;
  const int d4 = threadIdx.x << 2;
  const u16* base = gh + ((size_t)(b * SQ + c * TCH) * NQ) + d4;
  float p[4] = {1.f,1.f,1.f,1.f}, q[4] = {0.f,0.f,0.f,0.f};
  for (int t = 0; t < TCH; ++t){
    u16x4 gv = *(const u16x4*)(base + (size_t)t * NQ);
    u16x4 hv = *(const u16x4*)(base + (size_t)t * NQ + DQ);
    #pragma unroll
    for (int e = 0; e < 4; ++e){
      float a, bv; sig_ab(bf2f(gv[e]), bf2f(hv[e]), a, bv);
      p[e] *= a; q[e] = a * q[e] + bv;
    }
  }
  const size_t o = ((size_t)blockIdx.x << 10) + d4;
  *(f32x4*)(P + o) = f32x4{p[0], p[1], p[2], p[3]};
  *(f32x4*)(Q + o) = f32x4{q[0], q[1], q[2], q[3]};
}

// ---------------- scan phase 2: scan across chunks; also emits h_last --------
__global__ __launch_bounds__(256) void scan2(const float* __restrict__ P,
                                             const float* __restrict__ Q,
                                             float* __restrict__ hst,
                                             float* __restrict__ hlast){
  const int idx = blockIdx.x * 256 + threadIdx.x;   // 0..B*D-1
  const int b = idx >> 10, d = idx & 1023;
  float h = 0.5f;                                   // h0 = g(0) = 0.5
  for (int c = 0; c < CCH; ++c){
    const size_t o = ((size_t)(b * CCH + c) << 10) + d;
    hst[o] = h;
    h = P[o] * h + Q[o];
  }
  hlast[idx] = h;
}

// ---------------- scan phase 3 (fused): replay + residual [+ LN + cast] ------
// MODE 0: inp fp32 (= x), writes out bf16 + xn = LN(out) bf16  (layer 0)
// MODE 1: inp bf16,       writes out bf16 + xn = LN(out) bf16  (layer 1)
// MODE 2: inp bf16,       writes out fp32, no xn               (layer 2)
// Block = 256 threads = one full D-row; per-row LN = wave shfl reduce +
// 1 syncthreads/row with double-buffered scratch (red[t&1]).
template<int MODE>
__global__ __launch_bounds__(256) void scan3f(const u16* __restrict__ gh,
                                              const float* __restrict__ hst,
                                              const void* __restrict__ inp,
                                              void* __restrict__ outp,
                                              u16* __restrict__ xn,
                                              const float* __restrict__ gamma,
                                              const float* __restrict__ beta){
  const int b = blockIdx.x >> 6;
  const int c = blockIdx.x & 63;
  const int tid = threadIdx.x;
  const int d4 = tid << 2;
  const int wave = tid >> 6, lane = tid & 63;
  const size_t srow = (size_t)(b * SQ + c * TCH);
  const u16* base = gh + srow * NQ + d4;
  const size_t o = ((size_t)blockIdx.x << 10) + d4;
  f32x4 h0v = *(const f32x4*)(hst + o);
  float h[4] = {h0v[0], h0v[1], h0v[2], h0v[3]};
  __shared__ float red[2][8];
  f32x4 gv = {}, bvv = {};
  if (MODE != 2){
    gv  = *(const f32x4*)(gamma + d4);
    bvv = *(const f32x4*)(beta  + d4);
  }
  for (int t = 0; t < TCH; ++t){
    u16x4 gg = *(const u16x4*)(base + (size_t)t * NQ);
    u16x4 hh = *(const u16x4*)(base + (size_t)t * NQ + DQ);
    f32x4 iv;
    if (MODE == 0){
      iv = *(const f32x4*)((const float*)inp + (srow + t) * DQ + d4);
    } else {
      u16x4 ib = *(const u16x4*)((const u16*)inp + (srow + t) * DQ + d4);
      #pragma unroll
      for (int e = 0; e < 4; ++e) iv[e] = bf2f(ib[e]);
    }
    f32x4 ov;
    #pragma unroll
    for (int e = 0; e < 4; ++e){
      float a, bv; sig_ab(bf2f(gg[e]), bf2f(hh[e]), a, bv);
      h[e] = a * h[e] + bv;
      ov[e] = h[e] + iv[e];
    }
    if (MODE == 2){
      *(f32x4*)((float*)outp + (srow + t) * DQ + d4) = ov;
    } else {
      u16x4 ob;
      #pragma unroll
      for (int e = 0; e < 4; ++e) ob[e] = f2bf(ov[e]);
      *(u16x4*)((u16*)outp + (srow + t) * DQ + d4) = ob;
      // row LayerNorm (256 threads hold the whole row)
      float s  = ov[0] + ov[1] + ov[2] + ov[3];
      float s2 = ov[0]*ov[0] + ov[1]*ov[1] + ov[2]*ov[2] + ov[3]*ov[3];
      #pragma unroll
      for (int off = 32; off > 0; off >>= 1){
        s  += __shfl_down(s,  off);
        s2 += __shfl_down(s2, off);
      }
      const int rb = t & 1;
      if (lane == 0){ red[rb][wave] = s; red[rb][4 + wave] = s2; }
      __syncthreads();
      s  = red[rb][0] + red[rb][1] + red[rb][2] + red[rb][3];
      s2 = red[rb][4] + red[rb][5] + red[rb][6] + red[rb][7];
      const float mean = s * (1.f / DQ);
      float var = fmaxf(s2 * (1.f / DQ) - mean * mean, 0.f);
      const float rstd = rsqrtf(var + 1e-5f);
      u16x4 xo;
      #pragma unroll
      for (int e = 0; e < 4; ++e)
        xo[e] = f2bf((ov[e] - mean) * rstd * gv[e] + bvv[e]);
      *(u16x4*)(xn + (srow + t) * DQ + d4) = xo;
    }
  }
}

extern "C" void kernel_launch(void* const* d_in, const int* in_sizes, int n_in,
                              void* d_out, int out_size, void* d_ws, size_t ws_size,
                              hipStream_t stream) {
  const float* x     = (const float*)d_in[0];   // (8,4096,1024)
  const float* gamma = (const float*)d_in[1];   // (3,1024)
  const float* beta  = (const float*)d_in[2];   // (3,1024)
  const float* W     = (const float*)d_in[3];   // (3,1024,2048)
  const float* bias  = (const float*)d_in[4];   // (3,2048)
  float* out = (float*)d_out;                   // 33554432 + 3*8192 floats

  char* ws = (char*)d_ws;
  const size_t ACT = (size_t)MQ * DQ * 4;                 // 128 MiB region each
  u16*   bufA = (u16*)(ws);                               // bf16 out of layer 0
  u16*   bufB = (u16*)(ws + ACT);                         // bf16 out of layer 1
  u16*   gh   = (u16*)  (ws + 2 * ACT);                   // MQ*NQ bf16 = 128 MiB
  u16*   xn   = (u16*)  (ws + 3 * ACT);                   // MQ*DQ bf16 = 64 MiB
  u16*   WT   = (u16*)  (ws + 3 * ACT + (size_t)MQ * DQ * 2);
  float* Pa   = (float*)(ws + 3 * ACT + (size_t)MQ * DQ * 2 + (size_t)3 * NQ * KQ * 2);
  float* Qa   = Pa + (size_t)BQ * CCH * DQ;
  float* hst  = Qa + (size_t)BQ * CCH * DQ;

  wt_cast<<<dim3(KQ / 64, NQ / 64, 3), 256, 0, stream>>>(W, WT);

  // ---- layer 0 ----
  ln_cast<<<MQ, 256, 0, stream>>>(x, gamma, beta, xn);
  gemm_k8<<<dim3((NQ / 256) * (MQ / 256)), 512, 0, stream>>>(xn, WT, bias, gh);
  scan1<<<BQ * CCH, 256, 0, stream>>>(gh, Pa, Qa);
  scan2<<<(BQ * DQ) / 256, 256, 0, stream>>>(Pa, Qa, hst, out + (size_t)MQ * DQ);
  scan3f<0><<<BQ * CCH, 256, 0, stream>>>(gh, hst, x, bufA, xn,
                                          gamma + DQ, beta + DQ);
  // ---- layer 1 ----
  gemm_k8<<<dim3((NQ / 256) * (MQ / 256)), 512, 0, stream>>>(
      xn, WT + (size_t)NQ * KQ, bias + NQ, gh);
  scan1<<<BQ * CCH, 256, 0, stream>>>(gh, Pa, Qa);
  scan2<<<(BQ * DQ) / 256, 256, 0, stream>>>(Pa, Qa, hst,
                                             out + (size_t)MQ * DQ + BQ * DQ);
  scan3f<1><<<BQ * CCH, 256, 0, stream>>>(gh, hst, bufA, bufB, xn,
                                          gamma + 2 * DQ, beta + 2 * DQ);
  // ---- layer 2 ----
  gemm_k8<<<dim3((NQ / 256) * (MQ / 256)), 512, 0, stream>>>(
      xn, WT + (size_t)2 * NQ * KQ, bias + 2 * NQ, gh);
  scan1<<<BQ * CCH, 256, 0, stream>>>(gh, Pa, Qa);
  scan2<<<(BQ * DQ) / 256, 256, 0, stream>>>(Pa, Qa, hst,
                                             out + (size_t)MQ * DQ + 2 * BQ * DQ);
  scan3f<2><<<BQ * CCH, 256, 0, stream>>>(gh, hst, bufB, out, nullptr,
                                          nullptr, nullptr);
}

// Round 6
// 732.505 us; speedup vs baseline: 1.4502x; 1.1119x over previous
//
#include <hip/hip_runtime.h>

typedef unsigned short u16;
typedef unsigned int   u32;
typedef float  f32x2  __attribute__((ext_vector_type(2)));
typedef float  f32x4  __attribute__((ext_vector_type(4)));
typedef short  bf16x8 __attribute__((ext_vector_type(8)));
typedef u16    u16x4  __attribute__((ext_vector_type(4)));
typedef u32    u32x4  __attribute__((ext_vector_type(4)));

#define BQ 8
#define SQ 4096
#define DQ 1024
#define NQ 2048      // 2*D
#define MQ 32768     // B*S
#define KQ 1024
#define CCH 64       // chunks per sequence
#define TCH 64       // timesteps per chunk (CCH*TCH == SQ)
#define NT 16        // K-tiles (KQ/64)

__device__ __forceinline__ float bf2f(u16 u){
  union { u32 i; float f; } v; v.i = ((u32)u) << 16; return v.f;
}
__device__ __forceinline__ u16 f2bf(float f){
  union { float f; u32 i; } v; v.f = f;
  u32 r = v.i + 0x7fffu + ((v.i >> 16) & 1u);   // round-to-nearest-even
  return (u16)(r >> 16);
}

// a = 1 - sigmoid(gate) = sigmoid(-gate);  bv = sigmoid(gate) * g(hidden)
__device__ __forceinline__ void sig_ab(float gate, float hid, float& a, float& bv){
  float eg = __expf(gate);
  float a_ = __builtin_amdgcn_rcpf(1.f + eg);
  float z  = 1.f - a_;
  float eh = __expf(hid);
  float sg = eh * __builtin_amdgcn_rcpf(1.f + eh);
  float gval = (hid >= 0.f) ? (hid + 0.5f) : sg;
  a = a_; bv = z * gval;
}

__device__ __forceinline__ void gload_lds16(const u16* g, u16* l){
  __builtin_amdgcn_global_load_lds(
      (const __attribute__((address_space(1))) u32*)g,
      (__attribute__((address_space(3)))       u32*)l,
      16, 0, 0);
}

// ---------------- W transpose + bf16 cast: [L][K][N] f32 -> [L][N][K] bf16 ----
__global__ __launch_bounds__(256) void wt_cast(const float* __restrict__ W,
                                               u16* __restrict__ WT){
  __shared__ float t[64][65];
  const int l  = blockIdx.z;
  const int k0 = blockIdx.x << 6, n0 = blockIdx.y << 6;
  const float* Wl = W  + (size_t)l * KQ * NQ;
  u16*         Tl = WT + (size_t)l * NQ * KQ;
  const int c = threadIdx.x & 63, r4 = threadIdx.x >> 6;
  #pragma unroll
  for (int i = 0; i < 16; ++i){
    int r = i * 4 + r4;
    t[r][c] = Wl[(size_t)(k0 + r) * NQ + n0 + c];
  }
  __syncthreads();
  #pragma unroll
  for (int i = 0; i < 16; ++i){
    int r = i * 4 + r4;
    Tl[(size_t)(n0 + r) * KQ + k0 + c] = f2bf(t[c][r]);
  }
}

// ---------------- LayerNorm (fp32 in) + bf16 cast — layer 0 only -------------
__global__ __launch_bounds__(256) void ln_cast(const float* __restrict__ x,
                                               const float* __restrict__ gamma,
                                               const float* __restrict__ beta,
                                               u16* __restrict__ xn){
  const size_t row = blockIdx.x;
  const int tid = threadIdx.x;
  f32x4 xv = *(const f32x4*)(x + row * DQ + tid * 4);
  float s  = xv[0] + xv[1] + xv[2] + xv[3];
  float s2 = xv[0]*xv[0] + xv[1]*xv[1] + xv[2]*xv[2] + xv[3]*xv[3];
  #pragma unroll
  for (int off = 32; off > 0; off >>= 1){
    s  += __shfl_down(s,  off);
    s2 += __shfl_down(s2, off);
  }
  __shared__ float red[8];
  const int wave = tid >> 6, lane = tid & 63;
  if (lane == 0){ red[wave] = s; red[4 + wave] = s2; }
  __syncthreads();
  s  = red[0] + red[1] + red[2] + red[3];
  s2 = red[4] + red[5] + red[6] + red[7];
  const float mean = s * (1.f / DQ);
  float var = fmaxf(s2 * (1.f / DQ) - mean * mean, 0.f);
  const float rstd = rsqrtf(var + 1e-5f);
  f32x4 gv = *(const f32x4*)(gamma + tid * 4);
  f32x4 bv = *(const f32x4*)(beta  + tid * 4);
  u16x4 o;
  #pragma unroll
  for (int e = 0; e < 4; ++e) o[e] = f2bf((xv[e] - mean) * rstd * gv[e] + bv[e]);
  *(u16x4*)(xn + row * DQ + tid * 4) = o;
}

// ---------------- GEMM + fused gate math + chunk-aggregate epilogue ----------
// R6: B-tile pairs gate/hidden for the SAME d-range: qn=0 -> W cols
// [bn*128,+128) (gate), qn=1 -> [1024+bn*128,+128) (hidden). K-loop is
// byte-identical to R5 (1-barrier phases, counted vmcnt, reg-persistent
// fragments, conflicts=0). Epilogue:
//  * a = sigmoid(-gate), bv = sigmoid(gate)*g(hidden), rounded to bf16,
//    packed (a|bv<<16), ONE dword store per elem (64 coalesced dwords/thread
//    vs 128 scattered 2B stores in R5).
//  * per-chunk (P,Q) computed in-register from the ROUNDED a,bv (consistent
//    with scan3 replay): 4-row segment compose per lane, 2-step shfl_up
//    ordered scan across hi-groups, in-lane compose over i. Chunk = 64 rows
//    = (qm,wr) band exactly. Deletes the scan1 kernel (-134 MB read/layer).
__global__ __launch_bounds__(512, 2) void gemm_k8(const u16* __restrict__ A,
                                                  const u16* __restrict__ Bt,
                                                  const float* __restrict__ bias,
                                                  u32* __restrict__ abv,
                                                  float* __restrict__ pq){
  __shared__ u16 lds[2][2][2][8192];   // [buf][op][half][row*64+col] = 128 KiB
  const int bid = blockIdx.x;
  const int swz = ((bid & 7) << 7) | (bid >> 3);   // 1024 wgs, %8==0 -> bijective
  const int bn = swz & 7, bm = swz >> 3;           // XCD owns contiguous bm stripe
  const int m0 = bm << 8;
  const int tid = threadIdx.x;
  const int w = tid >> 6, lane = tid & 63;
  const int wr = w >> 2, wc = w & 3;               // 2M x 4N wave grid
  const int lr = lane & 15, hi = lane >> 4;
  const int sl8 = lane >> 3;                       // staging row-in-8 (== row&7)
  const int sslot = (lane & 7) ^ sl8;              // pre-swizzled global slot

  f32x4 acc[2][2][4][2] = {};                      // [qm][qn=gate/hid][i][j]
  bf16x8 afr[4][2];                                // current A half (32 VGPR)
  bf16x8 bf0[2][2], bf1[2][2];                     // gate/hid B frags

#define FENCE asm volatile("" ::: "memory")
#define BAR do { FENCE; __builtin_amdgcn_s_barrier(); FENCE; } while(0)

#define STAGE(op, hf, kt, pb_) do {                                            \
    const u16* gsrc_ = (op) ? Bt : A;                                          \
    const int rb_ = (op) ? ((bn << 7) + (hf) * 1024) : (m0 + ((hf) << 7));     \
    _Pragma("unroll")                                                          \
    for (int g_ = 0; g_ < 2; ++g_){                                            \
      const int row_ = (w << 4) + (g_ << 3) + sl8;                             \
      gload_lds16(gsrc_ + (size_t)(rb_ + row_) * KQ + ((kt) << 6) + (sslot << 3),\
                  &lds[pb_][op][hf][((w << 4) + (g_ << 3)) << 6]);             \
    }                                                                          \
  } while(0)

  // swizzled ds_read: logical (row, 16B-slot) -> byte row*128 + (slot^(row&7))*16
#define LDSRD(dst, base_, row_, slot_) do {                                    \
    const int r_ = (row_);                                                     \
    dst = *(const bf16x8*)((const char*)(base_) +                              \
          ((r_ << 7) + ((((slot_)) ^ (r_ & 7)) << 4)));                        \
  } while(0)

#define RD_A(hf) do {                                                          \
    const u16* Ah_ = &lds[pb][0][hf][0];                                       \
    _Pragma("unroll")                                                          \
    for (int i_ = 0; i_ < 4; ++i_)                                             \
      _Pragma("unroll")                                                        \
      for (int kk_ = 0; kk_ < 2; ++kk_)                                        \
        LDSRD(afr[i_][kk_], Ah_, (wr << 6) + (i_ << 4) + lr, (kk_ << 2) + hi); \
  } while(0)

#define RD_B(dst, hf) do {                                                     \
    const u16* Bh_ = &lds[pb][1][hf][0];                                       \
    _Pragma("unroll")                                                          \
    for (int j_ = 0; j_ < 2; ++j_)                                             \
      _Pragma("unroll")                                                        \
      for (int kk_ = 0; kk_ < 2; ++kk_)                                        \
        LDSRD(dst[j_][kk_], Bh_, (wc << 5) + (j_ << 4) + lr, (kk_ << 2) + hi); \
  } while(0)

#define MM(qm, qn, B) do {                                                     \
    _Pragma("unroll")                                                          \
    for (int i_ = 0; i_ < 4; ++i_)                                             \
      _Pragma("unroll")                                                        \
      for (int j_ = 0; j_ < 2; ++j_)                                           \
        _Pragma("unroll")                                                      \
        for (int kk_ = 0; kk_ < 2; ++kk_)                                      \
          acc[qm][qn][i_][j_] = __builtin_amdgcn_mfma_f32_16x16x32_bf16(       \
              afr[i_][kk_], B[j_][kk_], acc[qm][qn][i_][j_], 0, 0, 0);         \
  } while(0)

#define PH(VMW, STG, RDS, MFMAS) do {                                          \
    VMW;                                                                       \
    BAR;                                                                       \
    STG;                                                                       \
    RDS;                                                                       \
    asm volatile("s_waitcnt lgkmcnt(0)" ::: "memory");                         \
    __builtin_amdgcn_s_setprio(1);                                             \
    MFMAS;                                                                     \
    __builtin_amdgcn_s_setprio(0);                                             \
  } while(0)

  // prologue: stage tile0 into buf0, issue order B0,A0,B1,A1 (= steady state)
  STAGE(1, 0, 0, 0); STAGE(0, 0, 0, 0); STAGE(1, 1, 0, 0); STAGE(0, 1, 0, 0);

  for (int t = 0; t < NT; ++t){
    const int pb = t & 1, qb = pb ^ 1;
    const bool s = (t + 1 < NT);
    PH(asm volatile("s_waitcnt vmcnt(4)" ::: "memory"),
       if (s) STAGE(1, 0, t + 1, qb),                 // Bgate(t+1)
       RD_A(0); RD_B(bf0, 0),
       MM(0, 0, bf0));
    PH(if (s) { asm volatile("s_waitcnt vmcnt(4)" ::: "memory"); }
       else   { asm volatile("s_waitcnt vmcnt(2)" ::: "memory"); },
       if (s) STAGE(0, 0, t + 1, qb),                 // A0(t+1)
       RD_B(bf1, 1),
       MM(0, 1, bf1));
    PH(if (s) { asm volatile("s_waitcnt vmcnt(4)" ::: "memory"); }
       else   { asm volatile("s_waitcnt vmcnt(0)" ::: "memory"); },
       if (s) STAGE(1, 1, t + 1, qb),                 // Bhid(t+1)
       RD_A(1),
       MM(1, 0, bf0));
    PH(,
       if (s) STAGE(0, 1, t + 1, qb),                 // A1(t+1)
       ,
       MM(1, 1, bf1));
  }
#undef PH
#undef MM
#undef RD_B
#undef RD_A
#undef LDSRD
#undef STAGE

  // ---- fused epilogue: gate math + packed store + chunk (P,Q) aggregates ----
  const int dbase = (bn << 7) + (wc << 5) + lr;
  #pragma unroll
  for (int qm = 0; qm < 2; ++qm){
    const int row00 = m0 + (qm << 7) + (wr << 6);    // chunk base row
    float chP[2] = {1.f, 1.f}, chQ[2] = {0.f, 0.f};
    #pragma unroll
    for (int i = 0; i < 4; ++i){
      float sgP[2] = {1.f, 1.f}, sgQ[2] = {0.f, 0.f};
      #pragma unroll
      for (int r = 0; r < 4; ++r){
        const int row = row00 + (i << 4) + (hi << 2) + r;
        #pragma unroll
        for (int j = 0; j < 2; ++j){
          const int d = dbase + (j << 4);
          float gate = acc[qm][0][i][j][r] + bias[d];
          float hid  = acc[qm][1][i][j][r] + bias[1024 + d];
          float a, bv; sig_ab(gate, hid, a, bv);
          const u16 ua = f2bf(a), ub = f2bf(bv);
          abv[(size_t)row * 1024 + d] = (u32)ua | ((u32)ub << 16);
          const float ar = bf2f(ua), br = bf2f(ub);   // rounded (match replay)
          sgQ[j] = ar * sgQ[j] + br;                  // t ascending within seg
          sgP[j] *= ar;
        }
      }
      // ordered scan across hi-groups (lanes lr, lr+16, lr+32, lr+48)
      #pragma unroll
      for (int j = 0; j < 2; ++j){
        float p = sgP[j], q = sgQ[j];
        float p1 = __shfl_up(p, 16), q1 = __shfl_up(q, 16);
        if (hi >= 1){ q = p * q1 + q; p = p * p1; }
        float p2 = __shfl_up(p, 32), q2 = __shfl_up(q, 32);
        if (hi >= 2){ q = p * q2 + q; p = p * p2; }
        chQ[j] = p * chQ[j] + q;                      // compose i ascending
        chP[j] = p * chP[j];
      }
    }
    if (hi == 3){                                     // lane holds full chunk
      const int bq = row00 >> 12, cq = (row00 >> 6) & 63;
      #pragma unroll
      for (int j = 0; j < 2; ++j){
        const int d = dbase + (j << 4);
        f32x2 v; v[0] = chP[j]; v[1] = chQ[j];
        *(f32x2*)(pq + ((((size_t)(bq * CCH + cq)) << 10) + d) * 2) = v;
      }
    }
  }
#undef BAR
#undef FENCE
}

// ---------------- scan phase 2: scan across chunks; also emits h_last --------
__global__ __launch_bounds__(256) void scan2(const float* __restrict__ pq,
                                             float* __restrict__ hst,
                                             float* __restrict__ hlast){
  const int idx = blockIdx.x * 256 + threadIdx.x;   // 0..B*D-1
  const int b = idx >> 10, d = idx & 1023;
  float h = 0.5f;                                   // h0 = g(0) = 0.5
  for (int c = 0; c < CCH; ++c){
    const size_t o = ((size_t)(b * CCH + c) << 10) + d;
    hst[o] = h;
    f32x2 v = *(const f32x2*)(pq + o * 2);
    h = v[0] * h + v[1];
  }
  hlast[idx] = h;
}

// ---------------- scan phase 3 (fused): replay + residual [+ LN + cast] ------
// MODE 0: inp fp32 (= x), writes out bf16 + xn = LN(out) bf16  (layer 0)
// MODE 1: inp bf16,       writes out bf16 + xn = LN(out) bf16  (layer 1)
// MODE 2: inp bf16,       writes out fp32, no xn               (layer 2)
// Reads packed (a,bv) bf16 pairs — no exp in the replay loop.
template<int MODE>
__global__ __launch_bounds__(256) void scan3f(const u32* __restrict__ abv,
                                              const float* __restrict__ hst,
                                              const void* __restrict__ inp,
                                              void* __restrict__ outp,
                                              u16* __restrict__ xn,
                                              const float* __restrict__ gamma,
                                              const float* __restrict__ beta){
  const int b = blockIdx.x >> 6;
  const int c = blockIdx.x & 63;
  const int tid = threadIdx.x;
  const int d4 = tid << 2;
  const int wave = tid >> 6, lane = tid & 63;
  const size_t srow = (size_t)(b * SQ + c * TCH);
  const u32* base = abv + srow * 1024 + d4;
  const size_t o = ((size_t)blockIdx.x << 10) + d4;
  f32x4 h0v = *(const f32x4*)(hst + o);
  float h[4] = {h0v[0], h0v[1], h0v[2], h0v[3]};
  __shared__ float red[2][8];
  f32x4 gv = {}, bvv = {};
  if (MODE != 2){
    gv  = *(const f32x4*)(gamma + d4);
    bvv = *(const f32x4*)(beta  + d4);
  }
  for (int t = 0; t < TCH; ++t){
    u32x4 ab = *(const u32x4*)(base + (size_t)t * 1024);
    f32x4 iv;
    if (MODE == 0){
      iv = *(const f32x4*)((const float*)inp + (srow + t) * DQ + d4);
    } else {
      u16x4 ib = *(const u16x4*)((const u16*)inp + (srow + t) * DQ + d4);
      #pragma unroll
      for (int e = 0; e < 4; ++e) iv[e] = bf2f(ib[e]);
    }
    f32x4 ov;
    #pragma unroll
    for (int e = 0; e < 4; ++e){
      const float a  = bf2f((u16)(ab[e] & 0xffffu));
      const float bv = bf2f((u16)(ab[e] >> 16));
      h[e] = a * h[e] + bv;
      ov[e] = h[e] + iv[e];
    }
    if (MODE == 2){
      *(f32x4*)((float*)outp + (srow + t) * DQ + d4) = ov;
    } else {
      u16x4 ob;
      #pragma unroll
      for (int e = 0; e < 4; ++e) ob[e] = f2bf(ov[e]);
      *(u16x4*)((u16*)outp + (srow + t) * DQ + d4) = ob;
      // row LayerNorm (256 threads hold the whole row)
      float s  = ov[0] + ov[1] + ov[2] + ov[3];
      float s2 = ov[0]*ov[0] + ov[1]*ov[1] + ov[2]*ov[2] + ov[3]*ov[3];
      #pragma unroll
      for (int off = 32; off > 0; off >>= 1){
        s  += __shfl_down(s,  off);
        s2 += __shfl_down(s2, off);
      }
      const int rb = t & 1;
      if (lane == 0){ red[rb][wave] = s; red[rb][4 + wave] = s2; }
      __syncthreads();
      s  = red[rb][0] + red[rb][1] + red[rb][2] + red[rb][3];
      s2 = red[rb][4] + red[rb][5] + red[rb][6] + red[rb][7];
      const float mean = s * (1.f / DQ);
      float var = fmaxf(s2 * (1.f / DQ) - mean * mean, 0.f);
      const float rstd = rsqrtf(var + 1e-5f);
      u16x4 xo;
      #pragma unroll
      for (int e = 0; e < 4; ++e)
        xo[e] = f2bf((ov[e] - mean) * rstd * gv[e] + bvv[e]);
      *(u16x4*)(xn + (srow + t) * DQ + d4) = xo;
    }
  }
}

extern "C" void kernel_launch(void* const* d_in, const int* in_sizes, int n_in,
                              void* d_out, int out_size, void* d_ws, size_t ws_size,
                              hipStream_t stream) {
  const float* x     = (const float*)d_in[0];   // (8,4096,1024)
  const float* gamma = (const float*)d_in[1];   // (3,1024)
  const float* beta  = (const float*)d_in[2];   // (3,1024)
  const float* W     = (const float*)d_in[3];   // (3,1024,2048)
  const float* bias  = (const float*)d_in[4];   // (3,2048)
  float* out = (float*)d_out;                   // 33554432 + 3*8192 floats

  char* ws = (char*)d_ws;
  const size_t ACT = (size_t)MQ * DQ * 4;                 // 128 MiB region each
  u16*   bufA = (u16*)(ws);                               // bf16 out of layer 0
  u16*   bufB = (u16*)(ws + ACT);                         // bf16 out of layer 1
  u32*   abv  = (u32*)(ws + 2 * ACT);                     // MQ*1024 u32 = 128 MiB
  u16*   xn   = (u16*)(ws + 3 * ACT);                     // MQ*DQ bf16 = 64 MiB
  u16*   WT   = (u16*)(ws + 3 * ACT + (size_t)MQ * DQ * 2);
  float* pq   = (float*)(ws + 3 * ACT + (size_t)MQ * DQ * 2 + (size_t)3 * NQ * KQ * 2);
  float* hst  = pq + (size_t)2 * BQ * CCH * DQ;           // after 4 MiB pq

  wt_cast<<<dim3(KQ / 64, NQ / 64, 3), 256, 0, stream>>>(W, WT);

  const dim3 ggrid((NQ / 256) * (MQ / 256));
  // ---- layer 0 ----
  ln_cast<<<MQ, 256, 0, stream>>>(x, gamma, beta, xn);
  gemm_k8<<<ggrid, 512, 0, stream>>>(xn, WT, bias, abv, pq);
  scan2<<<(BQ * DQ) / 256, 256, 0, stream>>>(pq, hst, out + (size_t)MQ * DQ);
  scan3f<0><<<BQ * CCH, 256, 0, stream>>>(abv, hst, x, bufA, xn,
                                          gamma + DQ, beta + DQ);
  // ---- layer 1 ----
  gemm_k8<<<ggrid, 512, 0, stream>>>(xn, WT + (size_t)NQ * KQ, bias + NQ,
                                     abv, pq);
  scan2<<<(BQ * DQ) / 256, 256, 0, stream>>>(pq, hst,
                                             out + (size_t)MQ * DQ + BQ * DQ);
  scan3f<1><<<BQ * CCH, 256, 0, stream>>>(abv, hst, bufA, bufB, xn,
                                          gamma + 2 * DQ, beta + 2 * DQ);
  // ---- layer 2 ----
  gemm_k8<<<ggrid, 512, 0, stream>>>(xn, WT + (size_t)2 * NQ * KQ, bias + 2 * NQ,
                                     abv, pq);
  scan2<<<(BQ * DQ) / 256, 256, 0, stream>>>(pq, hst,
                                             out + (size_t)MQ * DQ + 2 * BQ * DQ);
  scan3f<2><<<BQ * CCH, 256, 0, stream>>>(abv, hst, bufB, out, nullptr,
                                          nullptr, nullptr);
}